// Round 8
// baseline (1033.843 us; speedup 1.0000x reference)
//
#include <hip/hip_runtime.h>
#include <hip/hip_bf16.h>
#include <stdint.h>

// Problem: B=4, N=2048, C=1024, H=16, D=64.
// Device dtypes: ALL inputs fp32, output fp32. Internal: bf16 MFMA, fp32 accum.
// x @ Wqkv.T -> RoPE(q,k) -> per-(b,h) softmax(q k^T /8 + mask) v -> @ Wproj.T + b

typedef __bf16 bf16;
typedef __bf16 bf16x4 __attribute__((ext_vector_type(4)));
typedef __bf16 bf16x8 __attribute__((ext_vector_type(8)));
typedef float  f32x4  __attribute__((ext_vector_type(4)));
typedef float  f32x16 __attribute__((ext_vector_type(16)));
typedef int    int4v  __attribute__((ext_vector_type(4)));

#define MFMA16(a, b, c) __builtin_amdgcn_mfma_f32_16x16x32_bf16((a), (b), (c), 0, 0, 0)
#define MFMA32(a, b, c) __builtin_amdgcn_mfma_f32_32x32x16_bf16((a), (b), (c), 0, 0, 0)

__device__ __forceinline__ bf16x4 cvt4s(float a, float b, float c, float d) {
  bf16x4 r;
  r[0] = (bf16)a; r[1] = (bf16)b; r[2] = (bf16)c; r[3] = (bf16)d;
  return r;
}
__device__ __forceinline__ bf16x8 cvt8(f32x4 a, f32x4 b) {
  bf16x8 r;
  r[0] = (bf16)a[0]; r[1] = (bf16)a[1]; r[2] = (bf16)a[2]; r[3] = (bf16)a[3];
  r[4] = (bf16)b[0]; r[5] = (bf16)b[1]; r[6] = (bf16)b[2]; r[7] = (bf16)b[3];
  return r;
}
__device__ __forceinline__ void gload16(const void* g, void* l) {
  __builtin_amdgcn_global_load_lds((const __attribute__((address_space(1))) void*)g,
                                   (__attribute__((address_space(3))) void*)l, 16, 0, 0);
}

// ---------------------------------------------------------------------------
// fp32 -> bf16 bulk convert (weights, once per launch)
// ---------------------------------------------------------------------------
__global__ __launch_bounds__(256)
void cvt_k(const float* __restrict__ W, bf16* __restrict__ Wb)
{
  const size_t i = ((size_t)blockIdx.x * 256 + threadIdx.x) * 8;
  const float* p = W + i;
  *(bf16x8*)(Wb + i) = cvt8(*(const f32x4*)p, *(const f32x4*)(p + 4));
}

// ---------------------------------------------------------------------------
// GEMM: C[m][n] = sum_k A[m][k] * B[n][k].  B is bf16 (pre-converted),
// staged via global_load_lds width-16.
// MODE 0: A = x (fp32, reg-cvt staging). Scatter: Q,K -> [BH][N][64] bf16,
//         V -> VT [BH][64][N] bf16. MODE 1: A = Ob (bf16, gload), + bias.
// ---------------------------------------------------------------------------
template<int MODE>
__global__ __launch_bounds__(256)
void gemm_bt(const void* __restrict__ Av, const bf16* __restrict__ B,
             void* __restrict__ O0, bf16* __restrict__ O1, bf16* __restrict__ O2,
             const float* __restrict__ bias)
{
  constexpr int K = 1024;
  __shared__ __attribute__((aligned(16))) bf16 As[128 * 64];
  __shared__ __attribute__((aligned(16))) bf16 Bs[128 * 64];
  const int tid = threadIdx.x, lane = tid & 63, wid = tid >> 6;
  const int m0 = blockIdx.x * 128, n0 = blockIdx.y * 128;
  const int wm = (wid >> 1) * 64, wn = (wid & 1) * 64;
  const int l15 = lane & 15, lg = lane >> 4;

  f32x4 acc[4][4] = {};

  for (int k0 = 0; k0 < K; k0 += 64) {
    // B tile: 128x64 bf16 via global_load_lds (4 segs/wave, 16B/lane)
#pragma unroll
    for (int c = 0; c < 4; ++c) {
      const int seg = wid * 4 + c;
      const int o = seg * 1024 + lane * 16;   // byte offset in 16KB tile
      const int row = o >> 7, colb = o & 127; // 128B per row (64 bf16)
      gload16((const char*)B + (((size_t)(n0 + row) * K + k0) << 1) + colb,
              (char*)Bs + seg * 1024);
    }
    if (MODE == 0) {
      const float* A = (const float*)Av;
#pragma unroll
      for (int it = 0; it < 4; ++it) {
        const int e = (it * 256 + tid) * 8;
        const int row = e >> 6, col = e & 63;
        const float* ap = A + (size_t)(m0 + row) * K + k0 + col;
        *(bf16x8*)(As + row * 64 + col) =
            cvt8(*(const f32x4*)ap, *(const f32x4*)(ap + 4));
      }
    } else {
      const bf16* A = (const bf16*)Av;
#pragma unroll
      for (int c = 0; c < 4; ++c) {
        const int seg = wid * 4 + c;
        const int o = seg * 1024 + lane * 16;
        const int row = o >> 7, colb = o & 127;
        gload16((const char*)A + (((size_t)(m0 + row) * K + k0) << 1) + colb,
                (char*)As + seg * 1024);
      }
    }
    __syncthreads();

    bf16x8 af[4][2], bb[4][2];
#pragma unroll
    for (int i = 0; i < 4; ++i)
#pragma unroll
      for (int kk = 0; kk < 2; ++kk) {
        af[i][kk] = *(const bf16x8*)(As + (wm + i * 16 + l15) * 64 + kk * 32 + lg * 8);
        bb[i][kk] = *(const bf16x8*)(Bs + (wn + i * 16 + l15) * 64 + kk * 32 + lg * 8);
      }
#pragma unroll
    for (int mi = 0; mi < 4; ++mi)
#pragma unroll
      for (int ni = 0; ni < 4; ++ni)
#pragma unroll
        for (int kk = 0; kk < 2; ++kk)
          acc[mi][ni] = MFMA16(af[mi][kk], bb[ni][kk], acc[mi][ni]);
    __syncthreads();
  }

#pragma unroll
  for (int mi = 0; mi < 4; ++mi)
#pragma unroll
    for (int ni = 0; ni < 4; ++ni)
#pragma unroll
      for (int r = 0; r < 4; ++r) {
        const int row = m0 + wm + mi * 16 + lg * 4 + r;
        const int col = n0 + wn + ni * 16 + l15;
        float v = acc[mi][ni][r];
        if (MODE == 0) {
          const int s = col >> 10, h = (col >> 6) & 15, d = col & 63;
          const int b = row >> 11, n = row & 2047;
          const bf16 bv = (bf16)v;
          if (s == 0)
            ((bf16*)O0)[(((size_t)(b * 16 + h) * 2048) + n) * 64 + d] = bv;
          else if (s == 1)
            O1[(((size_t)(b * 16 + h) * 2048) + n) * 64 + d] = bv;
          else
            O2[(((size_t)(b * 16 + h) * 64) + d) * 2048 + n] = bv;
        } else {
          ((float*)O0)[(size_t)row * 1024 + col] = v + bias[col];
        }
      }
}

// ---------------------------------------------------------------------------
// RoPE in place on Q and K ([BH][N][64] bf16). cos/sin fp32 [B][N][32].
// ---------------------------------------------------------------------------
__global__ __launch_bounds__(256)
void rope_k(bf16* __restrict__ Q, bf16* __restrict__ K,
            const float* __restrict__ C, const float* __restrict__ S)
{
  const int gid = blockIdx.x * 256 + threadIdx.x;
  const int part = gid & 3;
  const int rowid = gid >> 2;
  const int n = rowid & 2047;
  const int b = rowid >> 15;
  const size_t cbase = ((size_t)(b * 2048 + n)) * 32 + part * 8;

  float cf[8], sf[8];
  *(f32x4*)cf = *(const f32x4*)(C + cbase);
  *(f32x4*)(cf + 4) = *(const f32x4*)(C + cbase + 4);
  *(f32x4*)sf = *(const f32x4*)(S + cbase);
  *(f32x4*)(sf + 4) = *(const f32x4*)(S + cbase + 4);

  bf16* qp = Q + (size_t)rowid * 64 + part * 16;
  bf16* kp = K + (size_t)rowid * 64 + part * 16;
  __attribute__((aligned(16))) bf16 buf[16];

  *(int4v*)buf = *(const int4v*)qp;
  *(int4v*)(buf + 8) = *(const int4v*)(qp + 8);
#pragma unroll
  for (int j = 0; j < 8; ++j) {
    const float t0 = (float)buf[2 * j], t1 = (float)buf[2 * j + 1];
    buf[2 * j]     = (bf16)(t0 * cf[j] - t1 * sf[j]);
    buf[2 * j + 1] = (bf16)(t0 * sf[j] + t1 * cf[j]);
  }
  *(int4v*)qp = *(int4v*)buf;
  *(int4v*)(qp + 8) = *(int4v*)(buf + 8);

  *(int4v*)buf = *(const int4v*)kp;
  *(int4v*)(buf + 8) = *(const int4v*)(kp + 8);
#pragma unroll
  for (int j = 0; j < 8; ++j) {
    const float t0 = (float)buf[2 * j], t1 = (float)buf[2 * j + 1];
    buf[2 * j]     = (bf16)(t0 * cf[j] - t1 * sf[j]);
    buf[2 * j + 1] = (bf16)(t0 * sf[j] + t1 * cf[j]);
  }
  *(int4v*)kp = *(int4v*)buf;
  *(int4v*)(kp + 8) = *(int4v*)(buf + 8);
}

// ---------------------------------------------------------------------------
// Flash attention v6: v5 core + BLOCK-LOCAL KV-SPLIT x2 for occupancy.
// 512 threads = two 4-wave groups; group g handles kv in [g*1024, g*1024+1024)
// with its own Kt/Vt LDS; unnormalized o/li partials combined via LDS at end.
// Grid 1024 blocks -> 4 blocks/CU x 8 waves = 32 waves/CU (was 16).
// ---------------------------------------------------------------------------
__global__ __launch_bounds__(512, 8)
void attn_k(const bf16* __restrict__ Q, const bf16* __restrict__ K,
            const bf16* __restrict__ VT, const float* __restrict__ M,
            bf16* __restrict__ O)
{
  constexpr float SCALE_LOG2E = 0.125f * 1.4426950408889634f;
  constexpr float LOG2E = 1.4426950408889634f;
  // [0,16384): per-group Kt/Vt (g*8192).  Combine overlay (fp32): o-partials
  // [0,32KB) + li [32KB,32.5KB).  Epilogue ow overlay [0,18KB).  Total 33KB.
  __shared__ __attribute__((aligned(16))) bf16 SH[16896];

  const int tid = threadIdx.x, lane = tid & 63, w = tid >> 6;
  const int g = w >> 2, wg = w & 3, tg = tid & 255;
  const int bh = blockIdx.x;
  const int q0 = blockIdx.y * 128;
  const int b = bh >> 4, h = bh & 15;
  const int l31 = lane & 31, hi = lane >> 5;
  const int swz = (l31 & 7) << 3;

  bf16* Kt = SH + g * 8192;
  bf16* Vt = Kt + 4096;

  const bf16* Qb = Q + (size_t)bh * 2048 * 64;
  const bf16* Kb = K + (size_t)bh * 2048 * 64 + (size_t)g * 1024 * 64;
  const bf16* Vb = VT + (size_t)bh * 64 * 2048 + g * 1024;
  const float* Mq = M + (size_t)(q0 + wg * 32 + l31) * 2048 + g * 1024;

  // Q fragments: Q[q = q0+wg*32+l31][d = 16j + 8hi .. +7]
  bf16x8 qf[4];
  {
    const bf16* qr = Qb + (size_t)(q0 + wg * 32 + l31) * 64 + 8 * hi;
#pragma unroll
    for (int j = 0; j < 4; ++j) qf[j] = *(const bf16x8*)(qr + 16 * j);
  }

  f32x16 o[2] = {{0,0,0,0,0,0,0,0,0,0,0,0,0,0,0,0},
                 {0,0,0,0,0,0,0,0,0,0,0,0,0,0,0,0}};
  float li = 0.f;

  for (int kv0 = 0; kv0 < 1024; kv0 += 64) {
    // stage K [kv][d] and VT [d][kv] tiles (group-local), XOR-swizzled
#pragma unroll
    for (int it = 0; it < 2; ++it) {
      const int idx = it * 256 + tg;           // 0..511
      const int row = idx >> 3, g8 = (idx & 7) * 8;
      const int sc = g8 ^ ((row & 7) << 3);
      *(int4v*)(Kt + row * 64 + sc) =
          *(const int4v*)(Kb + (size_t)(kv0 + row) * 64 + g8);
      *(int4v*)(Vt + row * 64 + sc) =
          *(const int4v*)(Vb + (size_t)row * 2048 + kv0 + g8);
    }
    // mask prefetch (fp32, reg)
    f32x4 mk_all[2][4];
#pragma unroll
    for (int sub = 0; sub < 2; ++sub)
#pragma unroll
      for (int rg = 0; rg < 4; ++rg)
        mk_all[sub][rg] = *(const f32x4*)(Mq + kv0 + 32 * sub + 8 * rg + 4 * hi);

    __syncthreads();

#pragma unroll
    for (int sub = 0; sub < 2; ++sub) {
      // S^T[kv'][q] = sum_d K[kv'][d] Q[q][d]
      f32x16 s = {0,0,0,0,0,0,0,0,0,0,0,0,0,0,0,0};
#pragma unroll
      for (int j = 0; j < 4; ++j) {
        const bf16x8 kf = *(const bf16x8*)(
            Kt + (sub * 32 + l31) * 64 + ((16 * j + 8 * hi) ^ swz));
        s = MFMA32(kf, qf[j], s);
      }

      // static-max softmax: p = exp2(s*c + m*log2e)
      float rs = 0.f;
#pragma unroll
      for (int rg = 0; rg < 4; ++rg)
#pragma unroll
        for (int i = 0; i < 4; ++i) {
          const float p = __builtin_exp2f(
              fmaf(s[4 * rg + i], SCALE_LOG2E, mk_all[sub][rg][i] * LOG2E));
          s[4 * rg + i] = p;
          rs += p;
        }
      rs += __shfl_xor(rs, 32);
      li += rs;

      // T12: P -> bf16 in-register; permlane32_swap builds PV B-fragments
      uint32_t pk0, pk1, pk2, pk3, pk4, pk5, pk6, pk7;
      asm("v_cvt_pk_bf16_f32 %0, %1, %2" : "=v"(pk0) : "v"(s[0]),  "v"(s[1]));
      asm("v_cvt_pk_bf16_f32 %0, %1, %2" : "=v"(pk1) : "v"(s[2]),  "v"(s[3]));
      asm("v_cvt_pk_bf16_f32 %0, %1, %2" : "=v"(pk2) : "v"(s[4]),  "v"(s[5]));
      asm("v_cvt_pk_bf16_f32 %0, %1, %2" : "=v"(pk3) : "v"(s[6]),  "v"(s[7]));
      asm("v_cvt_pk_bf16_f32 %0, %1, %2" : "=v"(pk4) : "v"(s[8]),  "v"(s[9]));
      asm("v_cvt_pk_bf16_f32 %0, %1, %2" : "=v"(pk5) : "v"(s[10]), "v"(s[11]));
      asm("v_cvt_pk_bf16_f32 %0, %1, %2" : "=v"(pk6) : "v"(s[12]), "v"(s[13]));
      asm("v_cvt_pk_bf16_f32 %0, %1, %2" : "=v"(pk7) : "v"(s[14]), "v"(s[15]));
      asm("v_permlane32_swap_b32 %0, %1" : "+v"(pk0), "+v"(pk2));
      asm("v_permlane32_swap_b32 %0, %1" : "+v"(pk1), "+v"(pk3));
      asm("v_permlane32_swap_b32 %0, %1" : "+v"(pk4), "+v"(pk6));
      asm("v_permlane32_swap_b32 %0, %1" : "+v"(pk5), "+v"(pk7));
      uint32_t pau[2][4] = {{pk0, pk1, pk2, pk3}, {pk4, pk5, pk6, pk7}};
      bf16x8 pa[2];
      __builtin_memcpy(&pa[0], pau[0], 16);
      __builtin_memcpy(&pa[1], pau[1], 16);

      // PV: O^T[d'][q] += V^T[d'][kv] P^T[kv][q]
#pragma unroll
      for (int kh = 0; kh < 2; ++kh)
#pragma unroll
        for (int dblk = 0; dblk < 2; ++dblk) {
          const bf16x8 vf = *(const bf16x8*)(
              Vt + (dblk * 32 + l31) * 64 + ((sub * 32 + kh * 16 + 8 * hi) ^ swz));
          o[dblk] = MFMA32(vf, pa[kh], o[dblk]);
        }
    }
    __syncthreads();
  }

  // ---- combine the two kv-halves via LDS ----
  float* CB = (float*)SH;
  if (g == 1) {
    if (hi == 0) CB[8192 + wg * 32 + l31] = li;
    float* cb = CB + wg * 2048;  // [32 q][64 d], slot-XOR swizzled
#pragma unroll
    for (int dblk = 0; dblk < 2; ++dblk)
#pragma unroll
      for (int rg = 0; rg < 4; ++rg) {
        const int dbase = dblk * 32 + 8 * rg + 4 * hi;
        const int off = dbase ^ ((l31 & 15) << 2);
        *(f32x4*)(cb + l31 * 64 + off) =
            (f32x4){o[dblk][4 * rg], o[dblk][4 * rg + 1],
                    o[dblk][4 * rg + 2], o[dblk][4 * rg + 3]};
      }
  }
  __syncthreads();
  float inv = 0.f;
  if (g == 0) {
    const float li_tot = li + CB[8192 + wg * 32 + l31];
    float* cb = CB + wg * 2048;
#pragma unroll
    for (int dblk = 0; dblk < 2; ++dblk)
#pragma unroll
      for (int rg = 0; rg < 4; ++rg) {
        const int dbase = dblk * 32 + 8 * rg + 4 * hi;
        const f32x4 part = *(const f32x4*)(cb + l31 * 64 + (dbase ^ ((l31 & 15) << 2)));
#pragma unroll
        for (int i = 0; i < 4; ++i) o[dblk][4 * rg + i] += part[i];
      }
    inv = 1.f / li_tot;
  }
  __syncthreads();
  if (g == 1) return;

  // epilogue (group 0): normalize, transpose via LDS, coalesced b128 stores.
  bf16* ow = SH + wg * 2304;
#pragma unroll
  for (int dblk = 0; dblk < 2; ++dblk)
#pragma unroll
    for (int rg = 0; rg < 4; ++rg)
      *(bf16x4*)(ow + l31 * 72 + dblk * 32 + 8 * rg + 4 * hi) =
          cvt4s(o[dblk][4 * rg] * inv, o[dblk][4 * rg + 1] * inv,
                o[dblk][4 * rg + 2] * inv, o[dblk][4 * rg + 3] * inv);
  asm volatile("s_waitcnt lgkmcnt(0)" ::: "memory");
  __builtin_amdgcn_sched_barrier(0);
#pragma unroll
  for (int p = 0; p < 4; ++p) {
    const int row = p * 8 + (lane >> 3);
    const int n = q0 + wg * 32 + row;
    const int4v v = *(const int4v*)(ow + row * 72 + (lane & 7) * 8);
    *(int4v*)(O + ((size_t)b * 2048 + n) * 1024 + h * 64 + (lane & 7) * 8) = v;
  }
}

// ---------------------------------------------------------------------------
extern "C" void kernel_launch(void* const* d_in, const int* in_sizes, int n_in,
                              void* d_out, int out_size, void* d_ws, size_t ws_size,
                              hipStream_t stream)
{
  (void)in_sizes; (void)n_in; (void)out_size;
  const float* x     = (const float*)d_in[0];
  const float* fcos  = (const float*)d_in[1];
  const float* fsin  = (const float*)d_in[2];
  const float* mask  = (const float*)d_in[3];
  const float* wqkv  = (const float*)d_in[4];
  const float* wproj = (const float*)d_in[5];
  const float* bproj = (const float*)d_in[6];
  float* out = (float*)d_out;

  const size_t SZ = (size_t)64 * 2048 * 64 * 2;            // 16.78 MB
  const size_t WQB = (size_t)3072 * 1024 * 2;              // 6.29 MB
  const size_t WPB = (size_t)1024 * 1024 * 2;              // 2.10 MB
  if (ws_size < 4 * SZ + WQB + WPB) return;                // 75.5 MB (proven avail)
  char* ws = (char*)d_ws;
  bf16* Qr  = (bf16*)(ws);
  bf16* Kr  = (bf16*)(ws + SZ);
  bf16* VT  = (bf16*)(ws + 2 * SZ);
  bf16* Ob  = (bf16*)(ws + 3 * SZ);
  bf16* Wqb = (bf16*)(ws + 4 * SZ);
  bf16* Wpb = (bf16*)(ws + 4 * SZ + WQB);

  cvt_k<<<1536, 256, 0, stream>>>(wqkv, Wqb);
  cvt_k<<<512, 256, 0, stream>>>(wproj, Wpb);
  gemm_bt<0><<<dim3(64, 24), 256, 0, stream>>>(x, Wqb, Qr, Kr, VT, nullptr);
  rope_k<<<2048, 256, 0, stream>>>(Qr, Kr, fcos, fsin);
  attn_k<<<dim3(64, 16), 512, 0, stream>>>(Qr, Kr, VT, mask, Ob);
  gemm_bt<1><<<dim3(64, 8), 256, 0, stream>>>(Ob, Wpb, out, nullptr, nullptr, bproj);
}

// Round 9
// 304.786 us; speedup vs baseline: 3.3920x; 3.3920x over previous
//
#include <hip/hip_runtime.h>
#include <hip/hip_bf16.h>
#include <stdint.h>

// Problem: B=4, N=2048, C=1024, H=16, D=64.
// Device dtypes: ALL inputs fp32, output fp32. Internal: bf16 MFMA, fp32 accum.
// x @ Wqkv.T -> RoPE(q,k) -> per-(b,h) softmax(q k^T /8 + mask) v -> @ Wproj.T + b

typedef __bf16 bf16;
typedef __bf16 bf16x4 __attribute__((ext_vector_type(4)));
typedef __bf16 bf16x8 __attribute__((ext_vector_type(8)));
typedef float  f32x4  __attribute__((ext_vector_type(4)));
typedef float  f32x16 __attribute__((ext_vector_type(16)));
typedef int    int4v  __attribute__((ext_vector_type(4)));

#define MFMA16(a, b, c) __builtin_amdgcn_mfma_f32_16x16x32_bf16((a), (b), (c), 0, 0, 0)
#define MFMA32(a, b, c) __builtin_amdgcn_mfma_f32_32x32x16_bf16((a), (b), (c), 0, 0, 0)

__device__ __forceinline__ bf16x4 cvt4s(float a, float b, float c, float d) {
  bf16x4 r;
  r[0] = (bf16)a; r[1] = (bf16)b; r[2] = (bf16)c; r[3] = (bf16)d;
  return r;
}
__device__ __forceinline__ bf16x8 cvt8(f32x4 a, f32x4 b) {
  bf16x8 r;
  r[0] = (bf16)a[0]; r[1] = (bf16)a[1]; r[2] = (bf16)a[2]; r[3] = (bf16)a[3];
  r[4] = (bf16)b[0]; r[5] = (bf16)b[1]; r[6] = (bf16)b[2]; r[7] = (bf16)b[3];
  return r;
}
__device__ __forceinline__ void gload16(const void* g, void* l) {
  __builtin_amdgcn_global_load_lds((const __attribute__((address_space(1))) void*)g,
                                   (__attribute__((address_space(3))) void*)l, 16, 0, 0);
}

// ---------------------------------------------------------------------------
// fp32 -> bf16 bulk convert; optional scale (for mask * log2e).
// ---------------------------------------------------------------------------
__global__ __launch_bounds__(256)
void cvt_k(const float* __restrict__ W, bf16* __restrict__ Wb, float scale)
{
  const size_t i = ((size_t)blockIdx.x * 256 + threadIdx.x) * 8;
  const float* p = W + i;
  f32x4 a = *(const f32x4*)p * scale;
  f32x4 b = *(const f32x4*)(p + 4) * scale;
  *(bf16x8*)(Wb + i) = cvt8(a, b);
}

// ---------------------------------------------------------------------------
// GEMM: C[m][n] = sum_k A[m][k] * B[n][k].  B is bf16 (pre-converted),
// staged via global_load_lds width-16.
// MODE 0: A = x (fp32, reg-cvt staging). Scatter: Q,K -> [BH][N][64] bf16,
//         V -> VT [BH][64][N] bf16. MODE 1: A = Ob (bf16, gload), + bias.
// ---------------------------------------------------------------------------
template<int MODE>
__global__ __launch_bounds__(256)
void gemm_bt(const void* __restrict__ Av, const bf16* __restrict__ B,
             void* __restrict__ O0, bf16* __restrict__ O1, bf16* __restrict__ O2,
             const float* __restrict__ bias)
{
  constexpr int K = 1024;
  __shared__ __attribute__((aligned(16))) bf16 As[128 * 64];
  __shared__ __attribute__((aligned(16))) bf16 Bs[128 * 64];
  const int tid = threadIdx.x, lane = tid & 63, wid = tid >> 6;
  const int m0 = blockIdx.x * 128, n0 = blockIdx.y * 128;
  const int wm = (wid >> 1) * 64, wn = (wid & 1) * 64;
  const int l15 = lane & 15, lg = lane >> 4;

  f32x4 acc[4][4] = {};

  for (int k0 = 0; k0 < K; k0 += 64) {
#pragma unroll
    for (int c = 0; c < 4; ++c) {
      const int seg = wid * 4 + c;
      const int o = seg * 1024 + lane * 16;   // byte offset in 16KB tile
      const int row = o >> 7, colb = o & 127; // 128B per row (64 bf16)
      gload16((const char*)B + (((size_t)(n0 + row) * K + k0) << 1) + colb,
              (char*)Bs + seg * 1024);
    }
    if (MODE == 0) {
      const float* A = (const float*)Av;
#pragma unroll
      for (int it = 0; it < 4; ++it) {
        const int e = (it * 256 + tid) * 8;
        const int row = e >> 6, col = e & 63;
        const float* ap = A + (size_t)(m0 + row) * K + k0 + col;
        *(bf16x8*)(As + row * 64 + col) =
            cvt8(*(const f32x4*)ap, *(const f32x4*)(ap + 4));
      }
    } else {
      const bf16* A = (const bf16*)Av;
#pragma unroll
      for (int c = 0; c < 4; ++c) {
        const int seg = wid * 4 + c;
        const int o = seg * 1024 + lane * 16;
        const int row = o >> 7, colb = o & 127;
        gload16((const char*)A + (((size_t)(m0 + row) * K + k0) << 1) + colb,
                (char*)As + seg * 1024);
      }
    }
    __syncthreads();

    bf16x8 af[4][2], bb[4][2];
#pragma unroll
    for (int i = 0; i < 4; ++i)
#pragma unroll
      for (int kk = 0; kk < 2; ++kk) {
        af[i][kk] = *(const bf16x8*)(As + (wm + i * 16 + l15) * 64 + kk * 32 + lg * 8);
        bb[i][kk] = *(const bf16x8*)(Bs + (wn + i * 16 + l15) * 64 + kk * 32 + lg * 8);
      }
#pragma unroll
    for (int mi = 0; mi < 4; ++mi)
#pragma unroll
      for (int ni = 0; ni < 4; ++ni)
#pragma unroll
        for (int kk = 0; kk < 2; ++kk)
          acc[mi][ni] = MFMA16(af[mi][kk], bb[ni][kk], acc[mi][ni]);
    __syncthreads();
  }

#pragma unroll
  for (int mi = 0; mi < 4; ++mi)
#pragma unroll
    for (int ni = 0; ni < 4; ++ni)
#pragma unroll
      for (int r = 0; r < 4; ++r) {
        const int row = m0 + wm + mi * 16 + lg * 4 + r;
        const int col = n0 + wn + ni * 16 + l15;
        float v = acc[mi][ni][r];
        if (MODE == 0) {
          const int s = col >> 10, h = (col >> 6) & 15, d = col & 63;
          const int b = row >> 11, n = row & 2047;
          const bf16 bv = (bf16)v;
          if (s == 0)
            ((bf16*)O0)[(((size_t)(b * 16 + h) * 2048) + n) * 64 + d] = bv;
          else if (s == 1)
            O1[(((size_t)(b * 16 + h) * 2048) + n) * 64 + d] = bv;
          else
            O2[(((size_t)(b * 16 + h) * 64) + d) * 2048 + n] = bv;
        } else {
          ((float*)O0)[(size_t)row * 1024 + col] = v + bias[col];
        }
      }
}

// ---------------------------------------------------------------------------
// RoPE in place on Q and K ([BH][N][64] bf16). cos/sin fp32 [B][N][32].
// ---------------------------------------------------------------------------
__global__ __launch_bounds__(256)
void rope_k(bf16* __restrict__ Q, bf16* __restrict__ K,
            const float* __restrict__ C, const float* __restrict__ S)
{
  const int gid = blockIdx.x * 256 + threadIdx.x;
  const int part = gid & 3;
  const int rowid = gid >> 2;
  const int n = rowid & 2047;
  const int b = rowid >> 15;
  const size_t cbase = ((size_t)(b * 2048 + n)) * 32 + part * 8;

  float cf[8], sf[8];
  *(f32x4*)cf = *(const f32x4*)(C + cbase);
  *(f32x4*)(cf + 4) = *(const f32x4*)(C + cbase + 4);
  *(f32x4*)sf = *(const f32x4*)(S + cbase);
  *(f32x4*)(sf + 4) = *(const f32x4*)(S + cbase + 4);

  bf16* qp = Q + (size_t)rowid * 64 + part * 16;
  bf16* kp = K + (size_t)rowid * 64 + part * 16;
  __attribute__((aligned(16))) bf16 buf[16];

  *(int4v*)buf = *(const int4v*)qp;
  *(int4v*)(buf + 8) = *(const int4v*)(qp + 8);
#pragma unroll
  for (int j = 0; j < 8; ++j) {
    const float t0 = (float)buf[2 * j], t1 = (float)buf[2 * j + 1];
    buf[2 * j]     = (bf16)(t0 * cf[j] - t1 * sf[j]);
    buf[2 * j + 1] = (bf16)(t0 * sf[j] + t1 * cf[j]);
  }
  *(int4v*)qp = *(int4v*)buf;
  *(int4v*)(qp + 8) = *(int4v*)(buf + 8);

  *(int4v*)buf = *(const int4v*)kp;
  *(int4v*)(buf + 8) = *(const int4v*)(kp + 8);
#pragma unroll
  for (int j = 0; j < 8; ++j) {
    const float t0 = (float)buf[2 * j], t1 = (float)buf[2 * j + 1];
    buf[2 * j]     = (bf16)(t0 * cf[j] - t1 * sf[j]);
    buf[2 * j + 1] = (bf16)(t0 * sf[j] + t1 * cf[j]);
  }
  *(int4v*)kp = *(int4v*)buf;
  *(int4v*)(kp + 8) = *(int4v*)(buf + 8);
}

// ---------------------------------------------------------------------------
// Flash attention v7 = round-7 structure (mfma_32x32x16, swapped QK^T,
// static-max softmax, in-register P via cvt_pk+permlane32_swap, mask prefetch)
// + T5 s_setprio around MFMA clusters
// + (MM=1) mask pre-scaled to bf16*log2e: half the mask bytes, -8 held VGPRs.
//   MM=0 is the bit-identical round-7 fp32-mask fallback (ws-size guarded).
// 4 waves x 32 q-rows, 256 threads, launch_bounds(256,4). VGPR budget ~64+32.
// ---------------------------------------------------------------------------
template<int MM>
__global__ __launch_bounds__(256, 4)
void attn_k(const bf16* __restrict__ Q, const bf16* __restrict__ K,
            const bf16* __restrict__ VT, const void* __restrict__ Mv,
            bf16* __restrict__ O)
{
  constexpr float SCALE_LOG2E = 0.125f * 1.4426950408889634f;
  constexpr float LOG2E = 1.4426950408889634f;
  __shared__ __attribute__((aligned(16))) bf16 SH[9216];  // Kt 4096 | Vt 4096 ; epi 4x2304
  bf16* Kt = SH;
  bf16* Vt = SH + 4096;

  const int tid = threadIdx.x, lane = tid & 63, w = tid >> 6;
  const int bh = blockIdx.x;
  const int q0 = blockIdx.y * 128;
  const int b = bh >> 4, h = bh & 15;
  const int l31 = lane & 31, hi = lane >> 5;
  const int swz = (l31 & 7) << 3;

  const bf16* Qb = Q + (size_t)bh * 2048 * 64;
  const bf16* Kb = K + (size_t)bh * 2048 * 64;
  const bf16* Vb = VT + (size_t)bh * 64 * 2048;
  const float* Mqf = (const float*)Mv + (size_t)(q0 + w * 32 + l31) * 2048;
  const bf16*  Mqb = (const bf16*)Mv  + (size_t)(q0 + w * 32 + l31) * 2048;

  // Q fragments: Q[q = q0+w*32+l31][d = 16j + 8hi .. +7]
  bf16x8 qf[4];
  {
    const bf16* qr = Qb + (size_t)(q0 + w * 32 + l31) * 64 + 8 * hi;
#pragma unroll
    for (int j = 0; j < 4; ++j) qf[j] = *(const bf16x8*)(qr + 16 * j);
  }

  f32x16 o[2] = {{0,0,0,0,0,0,0,0,0,0,0,0,0,0,0,0},
                 {0,0,0,0,0,0,0,0,0,0,0,0,0,0,0,0}};
  float li = 0.f;

  for (int kv0 = 0; kv0 < 2048; kv0 += 64) {
    // stage K [kv][d] and VT [d][kv] tiles, XOR-swizzled, b128 in/out
#pragma unroll
    for (int it = 0; it < 2; ++it) {
      const int idx = it * 256 + tid;          // 0..511
      const int row = idx >> 3, g8 = (idx & 7) * 8;
      const int sc = g8 ^ ((row & 7) << 3);
      *(int4v*)(Kt + row * 64 + sc) =
          *(const int4v*)(Kb + (size_t)(kv0 + row) * 64 + g8);
      *(int4v*)(Vt + row * 64 + sc) =
          *(const int4v*)(Vb + (size_t)row * 2048 + kv0 + g8);
    }

    // MASK PREFETCH for the whole kv-tile (issued before the barrier).
    // lane needs M[q=l31][kv0 + 32*sub + 8*rg + 4*hi + 0..3]
    f32x4 mkf[2][4];
    bf16x4 mkb[2][4];
#pragma unroll
    for (int sub = 0; sub < 2; ++sub)
#pragma unroll
      for (int rg = 0; rg < 4; ++rg) {
        if (MM == 0)
          mkf[sub][rg] = *(const f32x4*)(Mqf + kv0 + 32 * sub + 8 * rg + 4 * hi);
        else
          mkb[sub][rg] = *(const bf16x4*)(Mqb + kv0 + 32 * sub + 8 * rg + 4 * hi);
      }

    __syncthreads();

#pragma unroll
    for (int sub = 0; sub < 2; ++sub) {
      // S^T[kv'][q] = sum_d K[kv'][d] Q[q][d]
      f32x16 s = {0,0,0,0,0,0,0,0,0,0,0,0,0,0,0,0};
      __builtin_amdgcn_s_setprio(1);
#pragma unroll
      for (int j = 0; j < 4; ++j) {
        const bf16x8 kf = *(const bf16x8*)(
            Kt + (sub * 32 + l31) * 64 + ((16 * j + 8 * hi) ^ swz));
        s = MFMA32(kf, qf[j], s);
      }
      __builtin_amdgcn_s_setprio(0);

      // static-max softmax: p = exp2(s*c + m'); row-sum: 16 local + 1 shfl
      float rs = 0.f;
#pragma unroll
      for (int rg = 0; rg < 4; ++rg)
#pragma unroll
        for (int i = 0; i < 4; ++i) {
          const float madd = (MM == 0) ? mkf[sub][rg][i] * LOG2E
                                       : (float)mkb[sub][rg][i];
          const float p = __builtin_exp2f(fmaf(s[4 * rg + i], SCALE_LOG2E, madd));
          s[4 * rg + i] = p;
          rs += p;
        }
      rs += __shfl_xor(rs, 32);
      li += rs;

      // T12: P -> bf16 pairs in-register, cross-half exchange builds B-frags.
      uint32_t pk0, pk1, pk2, pk3, pk4, pk5, pk6, pk7;
      asm("v_cvt_pk_bf16_f32 %0, %1, %2" : "=v"(pk0) : "v"(s[0]),  "v"(s[1]));
      asm("v_cvt_pk_bf16_f32 %0, %1, %2" : "=v"(pk1) : "v"(s[2]),  "v"(s[3]));
      asm("v_cvt_pk_bf16_f32 %0, %1, %2" : "=v"(pk2) : "v"(s[4]),  "v"(s[5]));
      asm("v_cvt_pk_bf16_f32 %0, %1, %2" : "=v"(pk3) : "v"(s[6]),  "v"(s[7]));
      asm("v_cvt_pk_bf16_f32 %0, %1, %2" : "=v"(pk4) : "v"(s[8]),  "v"(s[9]));
      asm("v_cvt_pk_bf16_f32 %0, %1, %2" : "=v"(pk5) : "v"(s[10]), "v"(s[11]));
      asm("v_cvt_pk_bf16_f32 %0, %1, %2" : "=v"(pk6) : "v"(s[12]), "v"(s[13]));
      asm("v_cvt_pk_bf16_f32 %0, %1, %2" : "=v"(pk7) : "v"(s[14]), "v"(s[15]));
      asm("v_permlane32_swap_b32 %0, %1" : "+v"(pk0), "+v"(pk2));
      asm("v_permlane32_swap_b32 %0, %1" : "+v"(pk1), "+v"(pk3));
      asm("v_permlane32_swap_b32 %0, %1" : "+v"(pk4), "+v"(pk6));
      asm("v_permlane32_swap_b32 %0, %1" : "+v"(pk5), "+v"(pk7));
      uint32_t pau[2][4] = {{pk0, pk1, pk2, pk3}, {pk4, pk5, pk6, pk7}};
      bf16x8 pa[2];
      __builtin_memcpy(&pa[0], pau[0], 16);
      __builtin_memcpy(&pa[1], pau[1], 16);

      // PV: O^T[d'][q] += V^T[d'][kv] P^T[kv][q]
      __builtin_amdgcn_s_setprio(1);
#pragma unroll
      for (int kh = 0; kh < 2; ++kh)
#pragma unroll
        for (int dblk = 0; dblk < 2; ++dblk) {
          const bf16x8 vf = *(const bf16x8*)(
              Vt + (dblk * 32 + l31) * 64 + ((sub * 32 + kh * 16 + 8 * hi) ^ swz));
          o[dblk] = MFMA32(vf, pa[kh], o[dblk]);
        }
      __builtin_amdgcn_s_setprio(0);
    }
    __syncthreads();
  }

  // epilogue: normalize (lane-local: li is for q = l31), transpose via LDS,
  // coalesced b128 global stores. Overlay: wave w -> SH + w*2304 ([32][72]).
  const float inv = 1.f / li;
  bf16* ow = SH + w * 2304;
#pragma unroll
  for (int dblk = 0; dblk < 2; ++dblk)
#pragma unroll
    for (int rg = 0; rg < 4; ++rg)
      *(bf16x4*)(ow + l31 * 72 + dblk * 32 + 8 * rg + 4 * hi) =
          cvt4s(o[dblk][4 * rg] * inv, o[dblk][4 * rg + 1] * inv,
                o[dblk][4 * rg + 2] * inv, o[dblk][4 * rg + 3] * inv);
  asm volatile("s_waitcnt lgkmcnt(0)" ::: "memory");
  __builtin_amdgcn_sched_barrier(0);
#pragma unroll
  for (int p = 0; p < 4; ++p) {
    const int row = p * 8 + (lane >> 3);
    const int n = q0 + w * 32 + row;
    const int4v v = *(const int4v*)(ow + row * 72 + (lane & 7) * 8);
    *(int4v*)(O + ((size_t)b * 2048 + n) * 1024 + h * 64 + (lane & 7) * 8) = v;
  }
}

// ---------------------------------------------------------------------------
extern "C" void kernel_launch(void* const* d_in, const int* in_sizes, int n_in,
                              void* d_out, int out_size, void* d_ws, size_t ws_size,
                              hipStream_t stream)
{
  (void)in_sizes; (void)n_in; (void)out_size;
  const float* x     = (const float*)d_in[0];
  const float* fcos  = (const float*)d_in[1];
  const float* fsin  = (const float*)d_in[2];
  const float* mask  = (const float*)d_in[3];
  const float* wqkv  = (const float*)d_in[4];
  const float* wproj = (const float*)d_in[5];
  const float* bproj = (const float*)d_in[6];
  float* out = (float*)d_out;

  const size_t SZ  = (size_t)64 * 2048 * 64 * 2;           // 16.78 MB
  const size_t WQB = (size_t)3072 * 1024 * 2;              // 6.29 MB
  const size_t WPB = (size_t)1024 * 1024 * 2;              // 2.10 MB
  const size_t MKB = (size_t)2048 * 2048 * 2;              // 8.39 MB (bf16 mask)
  const size_t BASE = 4 * SZ + WQB + WPB;                  // 75.5 MB (proven)
  if (ws_size < BASE) return;                              // fail loudly
  char* ws = (char*)d_ws;
  bf16* Qr  = (bf16*)(ws);
  bf16* Kr  = (bf16*)(ws + SZ);
  bf16* VT  = (bf16*)(ws + 2 * SZ);
  bf16* Ob  = (bf16*)(ws + 3 * SZ);
  bf16* Wqb = (bf16*)(ws + 4 * SZ);
  bf16* Wpb = (bf16*)(ws + 4 * SZ + WQB);
  bf16* Mb  = (bf16*)(ws + BASE);
  const bool useMb = (ws_size >= BASE + MKB);
  constexpr float LOG2E = 1.4426950408889634f;

  cvt_k<<<1536, 256, 0, stream>>>(wqkv, Wqb, 1.0f);
  cvt_k<<<512, 256, 0, stream>>>(wproj, Wpb, 1.0f);
  if (useMb) cvt_k<<<2048, 256, 0, stream>>>(mask, Mb, LOG2E);
  gemm_bt<0><<<dim3(64, 24), 256, 0, stream>>>(x, Wqb, Qr, Kr, VT, nullptr);
  rope_k<<<2048, 256, 0, stream>>>(Qr, Kr, fcos, fsin);
  if (useMb)
    attn_k<1><<<dim3(64, 16), 256, 0, stream>>>(Qr, Kr, VT, Mb, Ob);
  else
    attn_k<0><<<dim3(64, 16), 256, 0, stream>>>(Qr, Kr, VT, mask, Ob);
  gemm_bt<1><<<dim3(64, 8), 256, 0, stream>>>(Ob, Wpb, out, nullptr, nullptr, bproj);
}

// Round 10
// 301.263 us; speedup vs baseline: 3.4317x; 1.0117x over previous
//
#include <hip/hip_runtime.h>
#include <hip/hip_bf16.h>
#include <stdint.h>

// Problem: B=4, N=2048, C=1024, H=16, D=64.
// Device dtypes: ALL inputs fp32, output fp32. Internal: bf16 MFMA, fp32 accum.
// x @ Wqkv.T -> RoPE(q,k) -> per-(b,h) softmax(q k^T /8 + mask) v -> @ Wproj.T + b

typedef __bf16 bf16;
typedef __bf16 bf16x4 __attribute__((ext_vector_type(4)));
typedef __bf16 bf16x8 __attribute__((ext_vector_type(8)));
typedef float  f32x4  __attribute__((ext_vector_type(4)));
typedef float  f32x16 __attribute__((ext_vector_type(16)));
typedef int    int4v  __attribute__((ext_vector_type(4)));

#define MFMA16(a, b, c) __builtin_amdgcn_mfma_f32_16x16x32_bf16((a), (b), (c), 0, 0, 0)
#define MFMA32(a, b, c) __builtin_amdgcn_mfma_f32_32x32x16_bf16((a), (b), (c), 0, 0, 0)

__device__ __forceinline__ bf16x4 cvt4s(float a, float b, float c, float d) {
  bf16x4 r;
  r[0] = (bf16)a; r[1] = (bf16)b; r[2] = (bf16)c; r[3] = (bf16)d;
  return r;
}
__device__ __forceinline__ bf16x8 cvt8(f32x4 a, f32x4 b) {
  bf16x8 r;
  r[0] = (bf16)a[0]; r[1] = (bf16)a[1]; r[2] = (bf16)a[2]; r[3] = (bf16)a[3];
  r[4] = (bf16)b[0]; r[5] = (bf16)b[1]; r[6] = (bf16)b[2]; r[7] = (bf16)b[3];
  return r;
}
__device__ __forceinline__ void gload16(const void* g, void* l) {
  __builtin_amdgcn_global_load_lds((const __attribute__((address_space(1))) void*)g,
                                   (__attribute__((address_space(3))) void*)l, 16, 0, 0);
}

// ---------------------------------------------------------------------------
// fp32 -> bf16 bulk convert; optional scale (mask * log2e).
// ---------------------------------------------------------------------------
__global__ __launch_bounds__(256)
void cvt_k(const float* __restrict__ W, bf16* __restrict__ Wb, float scale)
{
  const size_t i = ((size_t)blockIdx.x * 256 + threadIdx.x) * 8;
  const float* p = W + i;
  f32x4 a = *(const f32x4*)p * scale;
  f32x4 b = *(const f32x4*)(p + 4) * scale;
  *(bf16x8*)(Wb + i) = cvt8(a, b);
}

// ---------------------------------------------------------------------------
// GEMM, m97 structure: C[m][n] = sum_k A[m][k]*B[n][k]; A,B bf16, both staged
// via global_load_lds width-16. MODE selects epilogue:
//   0: scatter Q,K -> [BH][N][64] bf16, V -> VT [BH][64][N] bf16.
//   1: + bias -> out fp32 [8192][1024].
// ---------------------------------------------------------------------------
template<int MODE>
__global__ __launch_bounds__(256)
void gemm_bt(const bf16* __restrict__ A, const bf16* __restrict__ B,
             void* __restrict__ O0, bf16* __restrict__ O1, bf16* __restrict__ O2,
             const float* __restrict__ bias)
{
  constexpr int K = 1024;
  __shared__ __attribute__((aligned(16))) bf16 As[128 * 64];
  __shared__ __attribute__((aligned(16))) bf16 Bs[128 * 64];
  const int tid = threadIdx.x, lane = tid & 63, wid = tid >> 6;
  const int m0 = blockIdx.x * 128, n0 = blockIdx.y * 128;
  const int wm = (wid >> 1) * 64, wn = (wid & 1) * 64;
  const int l15 = lane & 15, lg = lane >> 4;

  f32x4 acc[4][4] = {};

  for (int k0 = 0; k0 < K; k0 += 64) {
#pragma unroll
    for (int c = 0; c < 4; ++c) {
      const int seg = wid * 4 + c;
      const int o = seg * 1024 + lane * 16;   // byte offset in 16KB tile
      const int row = o >> 7, colb = o & 127; // 128B per row (64 bf16)
      gload16((const char*)B + (((size_t)(n0 + row) * K + k0) << 1) + colb,
              (char*)Bs + seg * 1024);
      gload16((const char*)A + (((size_t)(m0 + row) * K + k0) << 1) + colb,
              (char*)As + seg * 1024);
    }
    __syncthreads();

    bf16x8 af[4][2], bb[4][2];
#pragma unroll
    for (int i = 0; i < 4; ++i)
#pragma unroll
      for (int kk = 0; kk < 2; ++kk) {
        af[i][kk] = *(const bf16x8*)(As + (wm + i * 16 + l15) * 64 + kk * 32 + lg * 8);
        bb[i][kk] = *(const bf16x8*)(Bs + (wn + i * 16 + l15) * 64 + kk * 32 + lg * 8);
      }
#pragma unroll
    for (int mi = 0; mi < 4; ++mi)
#pragma unroll
      for (int ni = 0; ni < 4; ++ni)
#pragma unroll
        for (int kk = 0; kk < 2; ++kk)
          acc[mi][ni] = MFMA16(af[mi][kk], bb[ni][kk], acc[mi][ni]);
    __syncthreads();
  }

#pragma unroll
  for (int mi = 0; mi < 4; ++mi)
#pragma unroll
    for (int ni = 0; ni < 4; ++ni)
#pragma unroll
      for (int r = 0; r < 4; ++r) {
        const int row = m0 + wm + mi * 16 + lg * 4 + r;
        const int col = n0 + wn + ni * 16 + l15;
        float v = acc[mi][ni][r];
        if (MODE == 0) {
          const int s = col >> 10, h = (col >> 6) & 15, d = col & 63;
          const int b = row >> 11, n = row & 2047;
          const bf16 bv = (bf16)v;
          if (s == 0)
            ((bf16*)O0)[(((size_t)(b * 16 + h) * 2048) + n) * 64 + d] = bv;
          else if (s == 1)
            O1[(((size_t)(b * 16 + h) * 2048) + n) * 64 + d] = bv;
          else
            O2[(((size_t)(b * 16 + h) * 64) + d) * 2048 + n] = bv;
        } else {
          ((float*)O0)[(size_t)row * 1024 + col] = v + bias[col];
        }
      }
}

// ---------------------------------------------------------------------------
// RoPE in place on Q and K ([BH][N][64] bf16). cos/sin fp32 [B][N][32].
// Q additionally pre-scaled by SCALE*log2e (folded into cos/sin) so attention
// softmax is exp2(s) with no per-score fma.
// ---------------------------------------------------------------------------
__global__ __launch_bounds__(256)
void rope_k(bf16* __restrict__ Q, bf16* __restrict__ K,
            const float* __restrict__ C, const float* __restrict__ S)
{
  constexpr float SL = 0.125f * 1.4426950408889634f;
  const int gid = blockIdx.x * 256 + threadIdx.x;
  const int part = gid & 3;
  const int rowid = gid >> 2;
  const int n = rowid & 2047;
  const int b = rowid >> 15;
  const size_t cbase = ((size_t)(b * 2048 + n)) * 32 + part * 8;

  float cf[8], sf[8];
  *(f32x4*)cf = *(const f32x4*)(C + cbase);
  *(f32x4*)(cf + 4) = *(const f32x4*)(C + cbase + 4);
  *(f32x4*)sf = *(const f32x4*)(S + cbase);
  *(f32x4*)(sf + 4) = *(const f32x4*)(S + cbase + 4);

  bf16* qp = Q + (size_t)rowid * 64 + part * 16;
  bf16* kp = K + (size_t)rowid * 64 + part * 16;
  __attribute__((aligned(16))) bf16 buf[16];

  *(int4v*)buf = *(const int4v*)qp;
  *(int4v*)(buf + 8) = *(const int4v*)(qp + 8);
#pragma unroll
  for (int j = 0; j < 8; ++j) {
    const float t0 = (float)buf[2 * j], t1 = (float)buf[2 * j + 1];
    buf[2 * j]     = (bf16)((t0 * cf[j] - t1 * sf[j]) * SL);
    buf[2 * j + 1] = (bf16)((t0 * sf[j] + t1 * cf[j]) * SL);
  }
  *(int4v*)qp = *(int4v*)buf;
  *(int4v*)(qp + 8) = *(int4v*)(buf + 8);

  *(int4v*)buf = *(const int4v*)kp;
  *(int4v*)(buf + 8) = *(const int4v*)(kp + 8);
#pragma unroll
  for (int j = 0; j < 8; ++j) {
    const float t0 = (float)buf[2 * j], t1 = (float)buf[2 * j + 1];
    buf[2 * j]     = (bf16)(t0 * cf[j] - t1 * sf[j]);
    buf[2 * j + 1] = (bf16)(t0 * sf[j] + t1 * cf[j]);
  }
  *(int4v*)kp = *(int4v*)buf;
  *(int4v*)(kp + 8) = *(int4v*)(buf + 8);
}

// ---------------------------------------------------------------------------
// Flash attention v8: round-9 structure (mfma_32x32x16, swapped QK^T,
// static-max softmax, in-register P, mask prefetch, setprio) with the mask
// as the QK^T MFMA C-initializer and Q pre-scaled: p = exp2(s) directly.
// MM=1: mask bf16*log2e (ws-cached); MM=0: fp32 mask fallback.
// ---------------------------------------------------------------------------
template<int MM>
__global__ __launch_bounds__(256, 4)
void attn_k(const bf16* __restrict__ Q, const bf16* __restrict__ K,
            const bf16* __restrict__ VT, const void* __restrict__ Mv,
            bf16* __restrict__ O)
{
  constexpr float LOG2E = 1.4426950408889634f;
  __shared__ __attribute__((aligned(16))) bf16 SH[9216];  // Kt 4096 | Vt 4096 ; epi 4x2304
  bf16* Kt = SH;
  bf16* Vt = SH + 4096;

  const int tid = threadIdx.x, lane = tid & 63, w = tid >> 6;
  const int bh = blockIdx.x;
  const int q0 = blockIdx.y * 128;
  const int b = bh >> 4, h = bh & 15;
  const int l31 = lane & 31, hi = lane >> 5;
  const int swz = (l31 & 7) << 3;

  const bf16* Qb = Q + (size_t)bh * 2048 * 64;
  const bf16* Kb = K + (size_t)bh * 2048 * 64;
  const bf16* Vb = VT + (size_t)bh * 64 * 2048;
  const float* Mqf = (const float*)Mv + (size_t)(q0 + w * 32 + l31) * 2048;
  const bf16*  Mqb = (const bf16*)Mv  + (size_t)(q0 + w * 32 + l31) * 2048;

  bf16x8 qf[4];
  {
    const bf16* qr = Qb + (size_t)(q0 + w * 32 + l31) * 64 + 8 * hi;
#pragma unroll
    for (int j = 0; j < 4; ++j) qf[j] = *(const bf16x8*)(qr + 16 * j);
  }

  f32x16 o[2] = {{0,0,0,0,0,0,0,0,0,0,0,0,0,0,0,0},
                 {0,0,0,0,0,0,0,0,0,0,0,0,0,0,0,0}};
  float li = 0.f;

  for (int kv0 = 0; kv0 < 2048; kv0 += 64) {
#pragma unroll
    for (int it = 0; it < 2; ++it) {
      const int idx = it * 256 + tid;
      const int row = idx >> 3, g8 = (idx & 7) * 8;
      const int sc = g8 ^ ((row & 7) << 3);
      *(int4v*)(Kt + row * 64 + sc) =
          *(const int4v*)(Kb + (size_t)(kv0 + row) * 64 + g8);
      *(int4v*)(Vt + row * 64 + sc) =
          *(const int4v*)(Vb + (size_t)row * 2048 + kv0 + g8);
    }

    // mask prefetch: lane needs M[q=l31][kv0 + 32*sub + 8*rg + 4*hi + 0..3]
    f32x4 mkf[2][4];
    bf16x4 mkb[2][4];
#pragma unroll
    for (int sub = 0; sub < 2; ++sub)
#pragma unroll
      for (int rg = 0; rg < 4; ++rg) {
        if (MM == 0)
          mkf[sub][rg] = *(const f32x4*)(Mqf + kv0 + 32 * sub + 8 * rg + 4 * hi);
        else
          mkb[sub][rg] = *(const bf16x4*)(Mqb + kv0 + 32 * sub + 8 * rg + 4 * hi);
      }

    __syncthreads();

#pragma unroll
    for (int sub = 0; sub < 2; ++sub) {
      // S^T = K Q'^T with C initialized to mask*log2e (Q' pre-scaled)
      f32x16 s;
#pragma unroll
      for (int rg = 0; rg < 4; ++rg)
#pragma unroll
        for (int i = 0; i < 4; ++i)
          s[4 * rg + i] = (MM == 0) ? mkf[sub][rg][i] * LOG2E
                                    : (float)mkb[sub][rg][i];
      __builtin_amdgcn_s_setprio(1);
#pragma unroll
      for (int j = 0; j < 4; ++j) {
        const bf16x8 kf = *(const bf16x8*)(
            Kt + (sub * 32 + l31) * 64 + ((16 * j + 8 * hi) ^ swz));
        s = MFMA32(kf, qf[j], s);
      }
      __builtin_amdgcn_s_setprio(0);

      // softmax: p = exp2(s); row-sum 16 local + 1 shfl
      float rs = 0.f;
#pragma unroll
      for (int e = 0; e < 16; ++e) {
        const float p = __builtin_exp2f(s[e]);
        s[e] = p;
        rs += p;
      }
      rs += __shfl_xor(rs, 32);
      li += rs;

      // T12: P -> bf16 in-register; permlane32_swap builds PV B-fragments
      uint32_t pk0, pk1, pk2, pk3, pk4, pk5, pk6, pk7;
      asm("v_cvt_pk_bf16_f32 %0, %1, %2" : "=v"(pk0) : "v"(s[0]),  "v"(s[1]));
      asm("v_cvt_pk_bf16_f32 %0, %1, %2" : "=v"(pk1) : "v"(s[2]),  "v"(s[3]));
      asm("v_cvt_pk_bf16_f32 %0, %1, %2" : "=v"(pk2) : "v"(s[4]),  "v"(s[5]));
      asm("v_cvt_pk_bf16_f32 %0, %1, %2" : "=v"(pk3) : "v"(s[6]),  "v"(s[7]));
      asm("v_cvt_pk_bf16_f32 %0, %1, %2" : "=v"(pk4) : "v"(s[8]),  "v"(s[9]));
      asm("v_cvt_pk_bf16_f32 %0, %1, %2" : "=v"(pk5) : "v"(s[10]), "v"(s[11]));
      asm("v_cvt_pk_bf16_f32 %0, %1, %2" : "=v"(pk6) : "v"(s[12]), "v"(s[13]));
      asm("v_cvt_pk_bf16_f32 %0, %1, %2" : "=v"(pk7) : "v"(s[14]), "v"(s[15]));
      asm("v_permlane32_swap_b32 %0, %1" : "+v"(pk0), "+v"(pk2));
      asm("v_permlane32_swap_b32 %0, %1" : "+v"(pk1), "+v"(pk3));
      asm("v_permlane32_swap_b32 %0, %1" : "+v"(pk4), "+v"(pk6));
      asm("v_permlane32_swap_b32 %0, %1" : "+v"(pk5), "+v"(pk7));
      uint32_t pau[2][4] = {{pk0, pk1, pk2, pk3}, {pk4, pk5, pk6, pk7}};
      bf16x8 pa[2];
      __builtin_memcpy(&pa[0], pau[0], 16);
      __builtin_memcpy(&pa[1], pau[1], 16);

      // PV: O^T[d'][q] += V^T[d'][kv] P^T[kv][q]
      __builtin_amdgcn_s_setprio(1);
#pragma unroll
      for (int kh = 0; kh < 2; ++kh)
#pragma unroll
        for (int dblk = 0; dblk < 2; ++dblk) {
          const bf16x8 vf = *(const bf16x8*)(
              Vt + (dblk * 32 + l31) * 64 + ((sub * 32 + kh * 16 + 8 * hi) ^ swz));
          o[dblk] = MFMA32(vf, pa[kh], o[dblk]);
        }
      __builtin_amdgcn_s_setprio(0);
    }
    __syncthreads();
  }

  // epilogue: normalize (lane-local), transpose via LDS, b128 stores.
  const float inv = 1.f / li;
  bf16* ow = SH + w * 2304;
#pragma unroll
  for (int dblk = 0; dblk < 2; ++dblk)
#pragma unroll
    for (int rg = 0; rg < 4; ++rg)
      *(bf16x4*)(ow + l31 * 72 + dblk * 32 + 8 * rg + 4 * hi) =
          cvt4s(o[dblk][4 * rg] * inv, o[dblk][4 * rg + 1] * inv,
                o[dblk][4 * rg + 2] * inv, o[dblk][4 * rg + 3] * inv);
  asm volatile("s_waitcnt lgkmcnt(0)" ::: "memory");
  __builtin_amdgcn_sched_barrier(0);
#pragma unroll
  for (int p = 0; p < 4; ++p) {
    const int row = p * 8 + (lane >> 3);
    const int n = q0 + w * 32 + row;
    const int4v v = *(const int4v*)(ow + row * 72 + (lane & 7) * 8);
    *(int4v*)(O + ((size_t)b * 2048 + n) * 1024 + h * 64 + (lane & 7) * 8) = v;
  }
}

// ---------------------------------------------------------------------------
extern "C" void kernel_launch(void* const* d_in, const int* in_sizes, int n_in,
                              void* d_out, int out_size, void* d_ws, size_t ws_size,
                              hipStream_t stream)
{
  (void)in_sizes; (void)n_in; (void)out_size;
  const float* x     = (const float*)d_in[0];
  const float* fcos  = (const float*)d_in[1];
  const float* fsin  = (const float*)d_in[2];
  const float* mask  = (const float*)d_in[3];
  const float* wqkv  = (const float*)d_in[4];
  const float* wproj = (const float*)d_in[5];
  const float* bproj = (const float*)d_in[6];
  float* out = (float*)d_out;

  const size_t SZ  = (size_t)64 * 2048 * 64 * 2;           // 16.78 MB
  const size_t WQB = (size_t)3072 * 1024 * 2;              // 6.29 MB
  const size_t WPB = (size_t)1024 * 1024 * 2;              // 2.10 MB
  const size_t MKB = (size_t)2048 * 2048 * 2;              // 8.39 MB (bf16 mask)
  const size_t BASE = 4 * SZ + WQB + WPB;                  // 75.5 MB (proven)
  if (ws_size < BASE) return;                              // fail loudly
  char* ws = (char*)d_ws;
  bf16* Qr  = (bf16*)(ws);
  bf16* Kr  = (bf16*)(ws + SZ);
  bf16* VT  = (bf16*)(ws + 2 * SZ);
  bf16* Ob  = (bf16*)(ws + 3 * SZ);   // doubles as bf16(x) before attn runs
  bf16* Wqb = (bf16*)(ws + 4 * SZ);
  bf16* Wpb = (bf16*)(ws + 4 * SZ + WQB);
  bf16* Mb  = (bf16*)(ws + BASE);
  const bool useMb = (ws_size >= BASE + MKB);
  constexpr float LOG2E = 1.4426950408889634f;
  bf16* Xb = Ob;  // x-bf16 lives in the Ob slot (dead until attn)

  cvt_k<<<4096, 256, 0, stream>>>(x, Xb, 1.0f);
  cvt_k<<<1536, 256, 0, stream>>>(wqkv, Wqb, 1.0f);
  cvt_k<<<512, 256, 0, stream>>>(wproj, Wpb, 1.0f);
  if (useMb) cvt_k<<<2048, 256, 0, stream>>>(mask, Mb, LOG2E);
  gemm_bt<0><<<dim3(64, 24), 256, 0, stream>>>(Xb, Wqb, Qr, Kr, VT, nullptr);
  rope_k<<<2048, 256, 0, stream>>>(Qr, Kr, fcos, fsin);
  if (useMb)
    attn_k<1><<<dim3(64, 16), 256, 0, stream>>>(Qr, Kr, VT, Mb, Ob);
  else
    attn_k<0><<<dim3(64, 16), 256, 0, stream>>>(Qr, Kr, VT, mask, Ob);
  gemm_bt<1><<<dim3(64, 8), 256, 0, stream>>>(Ob, Wpb, out, nullptr, nullptr, bproj);
}